// Round 5
// baseline (484.928 us; speedup 1.0000x reference)
//
#include <hip/hip_runtime.h>
#include <hip/hip_cooperative_groups.h>
#include <math.h>

namespace cg = cooperative_groups;

#define NB   1024
#define NG   2000
#define NGS  25
#define KP   2048   // K padded to multiple of 64 for MFMA GEMM1
#define NH1  1024
#define NH2  512
#define NC   10
#define EPSV 1e-5f
#define GPB  200    // gene groups per block

typedef __attribute__((ext_vector_type(8)))  __bf16 bf16x8;
typedef __attribute__((ext_vector_type(4)))  float  f32x4;
typedef __attribute__((ext_vector_type(16))) float  f32x16;
typedef __attribute__((ext_vector_type(8)))  unsigned short u16x8;
typedef __attribute__((ext_vector_type(4)))  unsigned short u16x4;

__device__ __forceinline__ unsigned short f2bf(float f) {
  union { float f; unsigned u; } v; v.f = f;
  return (unsigned short)((v.u + 0x7fffu + ((v.u >> 16) & 1u)) >> 16);
}
__device__ __forceinline__ float bf2f(unsigned short b) {
  union { unsigned u; float f; } v; v.u = ((unsigned)b) << 16;
  return v.f;
}

// ---------------------------------------------------------------------------
// Prep + gene dispatch. grid (1024, 11):
//   y < 10 : gene layer block (batch row b = x, group-chunk y)
//   y == 10: x<512 -> convT W1 tile; x in [512,640) -> convT W2 tile;
//            x==640 -> zero BN stat accumulators; else idle.
// ---------------------------------------------------------------------------
__global__ __launch_bounds__(256) void prep_kernel(
    const float* __restrict__ x, const float* __restrict__ gw,
    const float* __restrict__ gb, unsigned short* __restrict__ g_bf,
    const float* __restrict__ W1, unsigned short* __restrict__ W1bT,
    const float* __restrict__ W2, unsigned short* __restrict__ W2bT,
    float* __restrict__ stats) {
  __shared__ char smem[GPB * NGS * 4];   // 20 KB, unioned between paths
  int t = threadIdx.x;

  if (blockIdx.y < 10) {                 // ---- gene path
    float* xs = (float*)smem;
    int b = blockIdx.x;
    int blk = blockIdx.y;
    const float4* src = (const float4*)(x + (size_t)b * (NG * NGS) + blk * (GPB * NGS));
    float4* dst = (float4*)xs;
    for (int i = t; i < (GPB * NGS) / 4; i += 256) dst[i] = src[i];
    __syncthreads();
    if (t < GPB) {
      int gi = blk * GPB + t;
      const float* wp = gw + gi * NGS;
      const float* xp = xs + t * NGS;
      float acc = 0.f;
#pragma unroll
      for (int k = 0; k < NGS; ++k) acc = fmaf(xp[k], wp[k], acc);
      acc += gb[gi];
      g_bf[(size_t)b * KP + gi] = f2bf(fmaxf(acc, 0.f));
    } else if (blk == 9 && t < GPB + (KP - NG)) {
      g_bf[(size_t)b * KP + NG + (t - GPB)] = 0;   // zero-pad k 2000..2047
    }
    return;
  }

  // ---- prep path (y == 10)
  int bx = blockIdx.x;
  if (bx == 640) {                       // zero BN stats (3072 floats)
    for (int i = t; i < 3072; i += 256) stats[i] = 0.f;
    return;
  }
  const float* src; unsigned short* dst; int K, N, Kpad, k0, n0;
  if (bx < 512)      { src = W1; dst = W1bT; K = NG;  N = NH1; Kpad = KP;
                       k0 = (bx & 31) * 64; n0 = (bx >> 5) * 64; }
  else if (bx < 640) { int xi = bx - 512;
                       src = W2; dst = W2bT; K = NH1; N = NH2; Kpad = NH1;
                       k0 = (xi & 15) * 64; n0 = (xi >> 4) * 64; }
  else return;

  unsigned short (*ts)[72] = (unsigned short (*)[72])smem;   // 64x72 = 9.2 KB
  int c4 = (t & 15) * 4;
  int r  = t >> 4;
  for (int rr = r; rr < 64; rr += 16) {
    int k = k0 + rr;
    float4 v = make_float4(0.f, 0.f, 0.f, 0.f);
    if (k < K) v = *(const float4*)&src[(size_t)k * N + n0 + c4];
    ts[rr][c4 + 0] = f2bf(v.x); ts[rr][c4 + 1] = f2bf(v.y);
    ts[rr][c4 + 2] = f2bf(v.z); ts[rr][c4 + 3] = f2bf(v.w);
  }
  __syncthreads();
  int rr8 = (t & 7) * 8;
  int cc  = t >> 3;
  for (int c = cc; c < 64; c += 32) {
    u16x8 val;
#pragma unroll
    for (int i = 0; i < 8; ++i) val[i] = ts[rr8 + i][c];
    *(u16x8*)&dst[(size_t)(n0 + c) * Kpad + k0 + rr8] = val;
  }
}

// ---------------------------------------------------------------------------
// Fused cooperative kernel, 512 blocks x 256 threads:
//   stage 1: GEMM1 t1 = g @ W1 (32x32x16 MFMA, 32x64 tile, waves split
//            n-half x k-phase, BK=128, LDS k-phase combine) + BN1 stats
//   stage 2: GEMM2 t2 = BN1(t1) @ W2 (16x16x32, 32x32 tile) + BN2 stats
//   stage 3: final heads + softmax, 2 batch rows per block
// grid.sync() between stages (BN stats are grid-wide dependencies).
// ---------------------------------------------------------------------------
__global__ __launch_bounds__(256) void fused_kernel(
    const unsigned short* __restrict__ g_bf,   // [NB][KP]
    const unsigned short* __restrict__ W1bT,   // [NH1][KP]
    const unsigned short* __restrict__ W2bT,   // [NH2][NH1]
    float* __restrict__ t1, float* __restrict__ t2,
    float* __restrict__ stats,
    const float* __restrict__ gam1, const float* __restrict__ bet1,
    const float* __restrict__ gam2, const float* __restrict__ bet2,
    const float* __restrict__ Wout, const float* __restrict__ bout,
    const float* __restrict__ Wres, const float* __restrict__ bres,
    float* __restrict__ out) {
  __shared__ char smem[26112];          // As1(8704) + Bs1(17408)
  __shared__ float red[4][NC];
  __shared__ float logits[NC];
  cg::grid_group grid = cg::this_grid();
  int t = threadIdx.x;
  int blk = blockIdx.x;
  int wave = t >> 6, lane = t & 63;

  // ---------------- stage 1: GEMM1 + BN1 stats --------------------------
  {
    unsigned short (*As)[136] = (unsigned short (*)[136])smem;          // 32 rows
    unsigned short (*Bs)[136] = (unsigned short (*)[136])(smem + 8704); // 64 rows
    int m0 = (blk >> 4) * 32;
    int n0 = (blk & 15) * 64;
    int h = wave & 1;          // n-half (32 cols)
    int p = wave >> 1;         // k-phase (64 of the 128-col LDS tile)
    int l31 = lane & 31, l5 = lane >> 5;

    int ar = t >> 3, ac = (t & 7) * 16;   // A staging: 32 rows x 128 cols
    int br = t >> 2, bc = (t & 3) * 32;   // B staging: 64 rows x 128 cols
    const unsigned short* Ap = g_bf + (size_t)(m0 + ar) * KP + ac;
    const unsigned short* Bp = W1bT + (size_t)(n0 + br) * KP + bc;

    f32x16 acc;
#pragma unroll
    for (int q = 0; q < 16; ++q) acc[q] = 0.f;

    u16x8 pa0 = *(const u16x8*)(Ap);
    u16x8 pa1 = *(const u16x8*)(Ap + 8);
    u16x8 pb0 = *(const u16x8*)(Bp);
    u16x8 pb1 = *(const u16x8*)(Bp + 8);
    u16x8 pb2 = *(const u16x8*)(Bp + 16);
    u16x8 pb3 = *(const u16x8*)(Bp + 24);

    for (int k0 = 0; k0 < KP; k0 += 128) {
      *(u16x8*)&As[ar][ac]      = pa0;
      *(u16x8*)&As[ar][ac + 8]  = pa1;
      *(u16x8*)&Bs[br][bc]      = pb0;
      *(u16x8*)&Bs[br][bc + 8]  = pb1;
      *(u16x8*)&Bs[br][bc + 16] = pb2;
      *(u16x8*)&Bs[br][bc + 24] = pb3;
      __syncthreads();
      if (k0 + 128 < KP) {
        pa0 = *(const u16x8*)(Ap + k0 + 128);
        pa1 = *(const u16x8*)(Ap + k0 + 136);
        pb0 = *(const u16x8*)(Bp + k0 + 128);
        pb1 = *(const u16x8*)(Bp + k0 + 136);
        pb2 = *(const u16x8*)(Bp + k0 + 144);
        pb3 = *(const u16x8*)(Bp + k0 + 152);
      }
      int cb = p * 64 + l5 * 8;
#pragma unroll
      for (int s = 0; s < 4; ++s) {
        bf16x8 av = *(const bf16x8*)&As[l31][cb + s * 16];
        bf16x8 bv = *(const bf16x8*)&Bs[h * 32 + l31][cb + s * 16];
        acc = __builtin_amdgcn_mfma_f32_32x32x16_bf16(av, bv, acc, 0, 0, 0);
      }
      __syncthreads();
    }
    // combine the two k-phases via LDS (alias Bs region, 8 KB)
    float* ebuf = (float*)(smem + 8704);
    if (p == 1) {
      float* dst = ebuf + (size_t)(h * 64 + lane) * 16;
#pragma unroll
      for (int q = 0; q < 4; ++q) {
        f32x4 v = {acc[q * 4], acc[q * 4 + 1], acc[q * 4 + 2], acc[q * 4 + 3]};
        *(f32x4*)(dst + q * 4) = v;
      }
    }
    __syncthreads();
    if (p == 0) {
      const float* src = ebuf + (size_t)(h * 64 + lane) * 16;
      float s = 0.f, ss = 0.f;
#pragma unroll
      for (int r = 0; r < 16; ++r) {
        float v = acc[r] + src[r];
        // C/D 32x32: col=lane&31, row=(r&3)+8*(r>>2)+4*(lane>>5)
        int row = m0 + (r & 3) + 8 * (r >> 2) + 4 * l5;
        t1[(size_t)row * NH1 + n0 + h * 32 + l31] = v;
        s += v;
        ss = fmaf(v, v, ss);
      }
      s  += __shfl_down(s, 32, 64);
      ss += __shfl_down(ss, 32, 64);
      if (lane < 32) {
        atomicAdd(&stats[n0 + h * 32 + lane], s);          // sum1
        atomicAdd(&stats[1024 + n0 + h * 32 + lane], ss);  // sq1
      }
    }
  }

  grid.sync();

  // ---------------- stage 2: GEMM2 (BN1 on A-staging) + BN2 stats -------
  {
    unsigned short (*As)[72] = (unsigned short (*)[72])smem;
    unsigned short (*Bs)[72] = (unsigned short (*)[72])(smem + 4608);
    const float* sum1 = stats;
    const float* sq1  = stats + 1024;
    float* sum2 = stats + 2048;
    float* sq2  = stats + 2560;
    int m0 = (blk >> 4) * 32, n0 = (blk & 15) * 32;
    int wm = (wave >> 1) * 16, wn = (wave & 1) * 16;
    int fm = lane & 15, fk = (lane >> 4) * 8;
    int srow = t >> 3, skc = (t & 7) * 8;

    f32x4 acc = {0.f, 0.f, 0.f, 0.f};

    const float* Ap = t1 + (size_t)(m0 + srow) * NH1 + skc;
    const unsigned short* Bp = W2bT + (size_t)(n0 + srow) * NH1 + skc;

    f32x4 pa0 = *(const f32x4*)(Ap);
    f32x4 pa1 = *(const f32x4*)(Ap + 4);
    u16x8 pb0 = *(const u16x8*)(Bp);

    for (int k0 = 0; k0 < NH1; k0 += 64) {
      float sc[8], sh[8];
#pragma unroll
      for (int i = 0; i < 8; ++i) {
        int k = k0 + skc + i;
        float mu  = sum1[k] * (1.f / NB);
        float var = sq1[k] * (1.f / NB) - mu * mu;
        float rs  = rsqrtf(var + EPSV);
        sc[i] = gam1[k] * rs;
        sh[i] = fmaf(-mu, sc[i], bet1[k]);
      }
      u16x8 a0;
#pragma unroll
      for (int i = 0; i < 4; ++i) {
        a0[i]     = f2bf(fmaxf(fmaf(pa0[i], sc[i],     sh[i]),     0.f));
        a0[i + 4] = f2bf(fmaxf(fmaf(pa1[i], sc[i + 4], sh[i + 4]), 0.f));
      }
      *(u16x8*)&As[srow][skc] = a0;
      *(u16x8*)&Bs[srow][skc] = pb0;
      __syncthreads();
      if (k0 + 64 < NH1) {
        pa0 = *(const f32x4*)(Ap + k0 + 64);
        pa1 = *(const f32x4*)(Ap + k0 + 64 + 4);
        pb0 = *(const u16x8*)(Bp + k0 + 64);
      }
#pragma unroll
      for (int s = 0; s < 2; ++s) {
        bf16x8 af = *(const bf16x8*)&As[wm + fm][s * 32 + fk];
        bf16x8 bf = *(const bf16x8*)&Bs[wn + fm][s * 32 + fk];
        acc = __builtin_amdgcn_mfma_f32_16x16x32_bf16(af, bf, acc, 0, 0, 0);
      }
      __syncthreads();
    }

    int crow = (lane >> 4) * 4, ccol = lane & 15;
    float s = 0.f, ss = 0.f;
#pragma unroll
    for (int r = 0; r < 4; ++r) {
      float v = acc[r];
      int m = m0 + wm + crow + r;
      int n = n0 + wn + ccol;
      t2[(size_t)m * NH2 + n] = v;
      s += v;
      ss = fmaf(v, v, ss);
    }
    s  += __shfl_down(s, 32, 64);  s  += __shfl_down(s, 16, 64);
    ss += __shfl_down(ss, 32, 64); ss += __shfl_down(ss, 16, 64);
    if (lane < 16) {
      atomicAdd(&sum2[n0 + wn + lane], s);
      atomicAdd(&sq2[n0 + wn + lane], ss);
    }
  }

  grid.sync();

  // ---------------- stage 3: heads + softmax (2 rows per block) ---------
  {
    const float* sum2 = stats + 2048;
    const float* sq2  = stats + 2560;
    for (int rr = 0; rr < 2; ++rr) {
      int b = blk * 2 + rr;
      __syncthreads();   // protect red/logits reuse across rr
      float acc[NC] = {};

      if (t < NH2 / 4) {   // main head, BN2 inline
        float4 tv = *(const float4*)&t2[(size_t)b * NH2 + t * 4];
        float raw[4] = {tv.x, tv.y, tv.z, tv.w};
        float hr[4];
#pragma unroll
        for (int i = 0; i < 4; ++i) {
          int c = t * 4 + i;
          float mu  = sum2[c] * (1.f / NB);
          float var = sq2[c] * (1.f / NB) - mu * mu;
          float rs  = rsqrtf(var + EPSV);
          float scv = gam2[c] * rs;
          hr[i] = fmaxf(fmaf(raw[i], scv, fmaf(-mu, scv, bet2[c])), 0.f);
        }
        const float4* wp = (const float4*)&Wout[t * 4 * NC];
        float w[40];
#pragma unroll
        for (int q = 0; q < 10; ++q) {
          float4 wv = wp[q];
          w[q * 4] = wv.x; w[q * 4 + 1] = wv.y; w[q * 4 + 2] = wv.z; w[q * 4 + 3] = wv.w;
        }
#pragma unroll
        for (int r = 0; r < 4; ++r)
#pragma unroll
          for (int c = 0; c < NC; ++c) acc[c] = fmaf(hr[r], w[r * NC + c], acc[c]);
      }

      for (int u = t; u < NG / 4; u += 256) {   // residual head
        u16x4 gv = *(const u16x4*)&g_bf[(size_t)b * KP + u * 4];
        float gr[4] = {bf2f(gv[0]), bf2f(gv[1]), bf2f(gv[2]), bf2f(gv[3])};
        const float4* wp = (const float4*)&Wres[u * 4 * NC];
        float w[40];
#pragma unroll
        for (int q = 0; q < 10; ++q) {
          float4 wv = wp[q];
          w[q * 4] = wv.x; w[q * 4 + 1] = wv.y; w[q * 4 + 2] = wv.z; w[q * 4 + 3] = wv.w;
        }
#pragma unroll
        for (int r = 0; r < 4; ++r)
#pragma unroll
          for (int c = 0; c < NC; ++c) acc[c] = fmaf(gr[r], w[r * NC + c], acc[c]);
      }

#pragma unroll
      for (int c = 0; c < NC; ++c) {
        float v = acc[c];
        for (int off = 32; off > 0; off >>= 1) v += __shfl_down(v, off, 64);
        if (lane == 0) red[wave][c] = v;
      }
      __syncthreads();
      if (t < NC)
        logits[t] = red[0][t] + red[1][t] + red[2][t] + red[3][t] + bout[t] + bres[t];
      __syncthreads();
      if (t == 0) {
        float mx = logits[0];
#pragma unroll
        for (int c = 1; c < NC; ++c) mx = fmaxf(mx, logits[c]);
        float e[NC], sm = 0.f;
#pragma unroll
        for (int c = 0; c < NC; ++c) { e[c] = expf(logits[c] - mx); sm += e[c]; }
        float inv = 1.f / sm;
#pragma unroll
        for (int c = 0; c < NC; ++c) out[(size_t)b * NC + c] = e[c] * inv;
      }
    }
  }
}

// ---------------------------------------------------------------------------
extern "C" void kernel_launch(void* const* d_in, const int* in_sizes, int n_in,
                              void* d_out, int out_size, void* d_ws, size_t ws_size,
                              hipStream_t stream) {
  const float* x      = (const float*)d_in[0];
  const float* gw     = (const float*)d_in[1];
  const float* gb     = (const float*)d_in[2];
  const float* W1     = (const float*)d_in[3];
  const float* gamma1 = (const float*)d_in[5];
  const float* beta1  = (const float*)d_in[6];
  const float* W2     = (const float*)d_in[7];
  const float* gamma2 = (const float*)d_in[9];
  const float* beta2  = (const float*)d_in[10];
  const float* Wout   = (const float*)d_in[11];
  const float* bout   = (const float*)d_in[12];
  const float* Wres   = (const float*)d_in[13];
  const float* bres   = (const float*)d_in[14];
  float* out = (float*)d_out;

  char* p = (char*)d_ws;
  unsigned short* g_bf = (unsigned short*)p; p += (size_t)NB * KP * 2;    // 4 MB
  unsigned short* W1bT = (unsigned short*)p; p += (size_t)NH1 * KP * 2;   // 4 MB
  unsigned short* W2bT = (unsigned short*)p; p += (size_t)NH2 * NH1 * 2;  // 1 MB
  float* t1 = (float*)p; p += (size_t)NB * NH1 * 4;                       // 4 MB
  float* t2 = (float*)p; p += (size_t)NB * NH2 * 4;                       // 2 MB
  float* stats = (float*)p;

  // gene + weight-transpose + stats-zero in one dispatch
  prep_kernel<<<dim3(NB, 11), 256, 0, stream>>>(x, gw, gb, g_bf,
                                                W1, W1bT, W2, W2bT, stats);

  void* args[] = {&g_bf, &W1bT, &W2bT, &t1, &t2, &stats,
                  (void*)&gamma1, (void*)&beta1, (void*)&gamma2, (void*)&beta2,
                  (void*)&Wout, (void*)&bout, (void*)&Wres, (void*)&bres, &out};
  hipLaunchCooperativeKernel((void*)fused_kernel, dim3(512), dim3(256),
                             args, 0, stream);
}

// Round 6
// 370.950 us; speedup vs baseline: 1.3073x; 1.3073x over previous
//
#include <hip/hip_runtime.h>
#include <math.h>

#define NB   1024
#define NG   2000
#define NGS  25
#define KP   2048   // K padded to multiple of 64 for MFMA GEMM1
#define NH1  1024
#define NH2  512
#define NC   10
#define EPSV 1e-5f
#define GPB  200    // gene groups per block

// R5 post-mortem: cooperative grid.sync() fusion cost +119 us (all pipes idle,
// MfmaUtil 1.5%) -- separate kernels are the cheaper grid barrier (~3 us/gap).
// Structure below is the R4 4-dispatch pipeline; t1 is now bf16 (BN1 stats
// from exact fp32 accumulators, BN1 applied on-the-fly in gemm2 staging).

typedef __attribute__((ext_vector_type(8))) __bf16 bf16x8;
typedef __attribute__((ext_vector_type(4))) float f32x4;
typedef __attribute__((ext_vector_type(8))) unsigned short u16x8;
typedef __attribute__((ext_vector_type(4))) unsigned short u16x4;

__device__ __forceinline__ unsigned short f2bf(float f) {
  union { float f; unsigned u; } v; v.f = f;
  return (unsigned short)((v.u + 0x7fffu + ((v.u >> 16) & 1u)) >> 16);
}
__device__ __forceinline__ float bf2f(unsigned short b) {
  union { unsigned u; float f; } v; v.u = ((unsigned)b) << 16;
  return v.f;
}

// ---------------------------------------------------------------------------
// Prep + gene dispatch. grid (1024, 11):
//   y < 10 : gene layer block (batch row b = x, group-chunk y)
//   y == 10: x<512 -> convT W1 tile; x in [512,640) -> convT W2 tile;
//            x==640 -> zero BN stat accumulators; else idle.
// ---------------------------------------------------------------------------
__global__ __launch_bounds__(256) void prep_kernel(
    const float* __restrict__ x, const float* __restrict__ gw,
    const float* __restrict__ gb, unsigned short* __restrict__ g_bf,
    const float* __restrict__ W1, unsigned short* __restrict__ W1bT,
    const float* __restrict__ W2, unsigned short* __restrict__ W2bT,
    float* __restrict__ stats) {
  __shared__ char smem[GPB * NGS * 4];   // 20 KB, unioned between paths
  int t = threadIdx.x;

  if (blockIdx.y < 10) {                 // ---- gene path
    float* xs = (float*)smem;
    int b = blockIdx.x;
    int blk = blockIdx.y;
    const float4* src = (const float4*)(x + (size_t)b * (NG * NGS) + blk * (GPB * NGS));
    float4* dst = (float4*)xs;
    for (int i = t; i < (GPB * NGS) / 4; i += 256) dst[i] = src[i];
    __syncthreads();
    if (t < GPB) {
      int gi = blk * GPB + t;
      const float* wp = gw + gi * NGS;
      const float* xp = xs + t * NGS;
      float acc = 0.f;
#pragma unroll
      for (int k = 0; k < NGS; ++k) acc = fmaf(xp[k], wp[k], acc);
      acc += gb[gi];
      g_bf[(size_t)b * KP + gi] = f2bf(fmaxf(acc, 0.f));
    } else if (blk == 9 && t < GPB + (KP - NG)) {
      g_bf[(size_t)b * KP + NG + (t - GPB)] = 0;   // zero-pad k 2000..2047
    }
    return;
  }

  // ---- prep path (y == 10)
  int bx = blockIdx.x;
  if (bx == 640) {                       // zero BN stats (3072 floats)
    for (int i = t; i < 3072; i += 256) stats[i] = 0.f;
    return;
  }
  const float* src; unsigned short* dst; int K, N, Kpad, k0, n0;
  if (bx < 512)      { src = W1; dst = W1bT; K = NG;  N = NH1; Kpad = KP;
                       k0 = (bx & 31) * 64; n0 = (bx >> 5) * 64; }
  else if (bx < 640) { int xi = bx - 512;
                       src = W2; dst = W2bT; K = NH1; N = NH2; Kpad = NH1;
                       k0 = (xi & 15) * 64; n0 = (xi >> 4) * 64; }
  else return;

  unsigned short (*ts)[72] = (unsigned short (*)[72])smem;   // 64x72 = 9.2 KB
  int c4 = (t & 15) * 4;
  int r  = t >> 4;
  for (int rr = r; rr < 64; rr += 16) {
    int k = k0 + rr;
    float4 v = make_float4(0.f, 0.f, 0.f, 0.f);
    if (k < K) v = *(const float4*)&src[(size_t)k * N + n0 + c4];
    ts[rr][c4 + 0] = f2bf(v.x); ts[rr][c4 + 1] = f2bf(v.y);
    ts[rr][c4 + 2] = f2bf(v.z); ts[rr][c4 + 3] = f2bf(v.w);
  }
  __syncthreads();
  int rr8 = (t & 7) * 8;
  int cc  = t >> 3;
  for (int c = cc; c < 64; c += 32) {
    u16x8 val;
#pragma unroll
    for (int i = 0; i < 8; ++i) val[i] = ts[rr8 + i][c];
    *(u16x8*)&dst[(size_t)(n0 + c) * Kpad + k0 + rr8] = val;
  }
}

// ---------------------------------------------------------------------------
// GEMM1: t1b(bf16) = A(bf16)[M][Kp] * Bt(bf16)[N][Kp]^T, fused BN1 stats
// (stats from exact fp32 accumulators, output rounded to bf16).
// 32x64 block tile (grid 512 = 2 blocks/CU -> 2 waves/SIMD), 4 waves each
// 16x64 (1 A-frag x 2 B-frags of 16x16x32). Padded LDS rows (72).
// ---------------------------------------------------------------------------
__global__ __launch_bounds__(256) void gemm1_kernel(
    const unsigned short* __restrict__ A,    // [M][Kp]
    const unsigned short* __restrict__ Bt,   // [N][Kp]
    unsigned short* __restrict__ C, float* __restrict__ sum,
    float* __restrict__ sq, int M, int N, int Kp) {
  __shared__ unsigned short As[32][72];
  __shared__ unsigned short Bs[64][72];
  int t = threadIdx.x;
  int m0 = blockIdx.y * 32, n0 = blockIdx.x * 64;
  int wave = t >> 6, lane = t & 63;
  int wm = (wave >> 1) * 16, wn = (wave & 1) * 32;
  int fm = lane & 15, fk = (lane >> 4) * 8;
  int srow = t >> 3, skc = (t & 7) * 8;    // srow 0..31

  f32x4 acc[2];
  acc[0] = (f32x4){0.f, 0.f, 0.f, 0.f};
  acc[1] = (f32x4){0.f, 0.f, 0.f, 0.f};

  const unsigned short* Ap = A + (size_t)(m0 + srow) * Kp + skc;
  const unsigned short* Bp = Bt + (size_t)(n0 + srow) * Kp + skc;
  size_t rstep = 32 * (size_t)Kp;

  u16x8 pa0 = *(const u16x8*)(Ap);
  u16x8 pb0 = *(const u16x8*)(Bp);
  u16x8 pb1 = *(const u16x8*)(Bp + rstep);

  for (int k0 = 0; k0 < Kp; k0 += 64) {
    *(u16x8*)&As[srow][skc]      = pa0;
    *(u16x8*)&Bs[srow][skc]      = pb0;
    *(u16x8*)&Bs[srow + 32][skc] = pb1;
    __syncthreads();
    if (k0 + 64 < Kp) {
      pa0 = *(const u16x8*)(Ap + k0 + 64);
      pb0 = *(const u16x8*)(Bp + k0 + 64);
      pb1 = *(const u16x8*)(Bp + k0 + 64 + rstep);
    }
#pragma unroll
    for (int s = 0; s < 2; ++s) {
      bf16x8 af = *(const bf16x8*)&As[wm + fm][s * 32 + fk];
      bf16x8 b0 = *(const bf16x8*)&Bs[wn + fm][s * 32 + fk];
      bf16x8 b1 = *(const bf16x8*)&Bs[wn + 16 + fm][s * 32 + fk];
      acc[0] = __builtin_amdgcn_mfma_f32_16x16x32_bf16(af, b0, acc[0], 0, 0, 0);
      acc[1] = __builtin_amdgcn_mfma_f32_16x16x32_bf16(af, b1, acc[1], 0, 0, 0);
    }
    __syncthreads();
  }

  int crow = (lane >> 4) * 4, ccol = lane & 15;
#pragma unroll
  for (int j = 0; j < 2; ++j) {
    float s = 0.f, ss = 0.f;
#pragma unroll
    for (int r = 0; r < 4; ++r) {
      float v = acc[j][r];
      int m = m0 + wm + crow + r;
      int n = n0 + wn + j * 16 + ccol;
      C[(size_t)m * N + n] = f2bf(v);
      s += v;
      ss = fmaf(v, v, ss);
    }
    s  += __shfl_down(s, 32, 64);  s  += __shfl_down(s, 16, 64);
    ss += __shfl_down(ss, 32, 64); ss += __shfl_down(ss, 16, 64);
    if (lane < 16) {
      atomicAdd(&sum[n0 + wn + j * 16 + lane], s);
      atomicAdd(&sq[n0 + wn + j * 16 + lane], ss);
    }
  }
}

// ---------------------------------------------------------------------------
// GEMM2: A = t1b bf16, BN1+ReLU applied during LDS staging; B = W2bT bf16.
// Fused BN2 stats. 32x32 tile (grid 512 = 2 blocks/CU), 4 waves each 16x16.
// ---------------------------------------------------------------------------
__global__ __launch_bounds__(256) void gemm2_kernel(
    const unsigned short* __restrict__ A,    // [M][Kp] bf16 (t1, pre-BN)
    const unsigned short* __restrict__ Bt,   // [N][Kp] bf16
    float* __restrict__ C, const float* __restrict__ sum1,
    const float* __restrict__ sq1, const float* __restrict__ gam1,
    const float* __restrict__ bet1, float* __restrict__ sum2,
    float* __restrict__ sq2, int M, int N, int Kp) {
  __shared__ unsigned short As[32][72];
  __shared__ unsigned short Bs[32][72];
  int t = threadIdx.x;
  int m0 = blockIdx.y * 32, n0 = blockIdx.x * 32;
  int wave = t >> 6, lane = t & 63;
  int wm = (wave >> 1) * 16, wn = (wave & 1) * 16;
  int fm = lane & 15, fk = (lane >> 4) * 8;
  int srow = t >> 3, skc = (t & 7) * 8;    // srow 0..31

  f32x4 acc = (f32x4){0.f, 0.f, 0.f, 0.f};

  const unsigned short* Ap = A + (size_t)(m0 + srow) * Kp + skc;
  const unsigned short* Bp = Bt + (size_t)(n0 + srow) * Kp + skc;

  u16x8 pa0 = *(const u16x8*)(Ap);
  u16x8 pb0 = *(const u16x8*)(Bp);

  for (int k0 = 0; k0 < Kp; k0 += 64) {
    // BN1 scale/shift for k = k0+skc+i (same 64 values block-wide -> L1 hot)
    float sc[8], sh[8];
#pragma unroll
    for (int i = 0; i < 8; ++i) {
      int k = k0 + skc + i;
      float mu  = sum1[k] * (1.f / NB);
      float var = sq1[k] * (1.f / NB) - mu * mu;
      float rs  = rsqrtf(var + EPSV);
      sc[i] = gam1[k] * rs;
      sh[i] = fmaf(-mu, sc[i], bet1[k]);
    }
    u16x8 a0;
#pragma unroll
    for (int i = 0; i < 8; ++i)
      a0[i] = f2bf(fmaxf(fmaf(bf2f(pa0[i]), sc[i], sh[i]), 0.f));
    *(u16x8*)&As[srow][skc] = a0;
    *(u16x8*)&Bs[srow][skc] = pb0;
    __syncthreads();
    if (k0 + 64 < Kp) {
      pa0 = *(const u16x8*)(Ap + k0 + 64);
      pb0 = *(const u16x8*)(Bp + k0 + 64);
    }
#pragma unroll
    for (int s = 0; s < 2; ++s) {
      bf16x8 af = *(const bf16x8*)&As[wm + fm][s * 32 + fk];
      bf16x8 bf = *(const bf16x8*)&Bs[wn + fm][s * 32 + fk];
      acc = __builtin_amdgcn_mfma_f32_16x16x32_bf16(af, bf, acc, 0, 0, 0);
    }
    __syncthreads();
  }

  int crow = (lane >> 4) * 4, ccol = lane & 15;
  float s = 0.f, ss = 0.f;
#pragma unroll
  for (int r = 0; r < 4; ++r) {
    float v = acc[r];
    int m = m0 + wm + crow + r;
    int n = n0 + wn + ccol;
    C[(size_t)m * N + n] = v;
    s += v;
    ss = fmaf(v, v, ss);
  }
  s  += __shfl_down(s, 32, 64);  s  += __shfl_down(s, 16, 64);
  ss += __shfl_down(ss, 32, 64); ss += __shfl_down(ss, 16, 64);
  if (lane < 16) {
    atomicAdd(&sum2[n0 + wn + lane], s);
    atomicAdd(&sq2[n0 + wn + lane], ss);
  }
}

// ---------------------------------------------------------------------------
// Final: BN2(inline)+ReLU on t2 row, both heads, softmax. Block per row.
// ---------------------------------------------------------------------------
__global__ __launch_bounds__(256) void final_kernel(
    const float* __restrict__ t2, const float* __restrict__ sum2,
    const float* __restrict__ sq2, const float* __restrict__ gam2,
    const float* __restrict__ bet2, const unsigned short* __restrict__ g_bf,
    const float* __restrict__ Wout, const float* __restrict__ bout,
    const float* __restrict__ Wres, const float* __restrict__ bres,
    float* __restrict__ out) {
  int b = blockIdx.x;
  int t = threadIdx.x;
  float acc[NC] = {};

  if (t < NH2 / 4) {   // main head: BN2 inline
    float4 tv = *(const float4*)&t2[(size_t)b * NH2 + t * 4];
    float raw[4] = {tv.x, tv.y, tv.z, tv.w};
    float hr[4];
#pragma unroll
    for (int i = 0; i < 4; ++i) {
      int c = t * 4 + i;
      float mu  = sum2[c] * (1.f / NB);
      float var = sq2[c] * (1.f / NB) - mu * mu;
      float rs  = rsqrtf(var + EPSV);
      float scv = gam2[c] * rs;
      hr[i] = fmaxf(fmaf(raw[i], scv, fmaf(-mu, scv, bet2[c])), 0.f);
    }
    const float4* wp = (const float4*)&Wout[t * 4 * NC];
    float w[40];
#pragma unroll
    for (int q = 0; q < 10; ++q) {
      float4 wv = wp[q];
      w[q * 4] = wv.x; w[q * 4 + 1] = wv.y; w[q * 4 + 2] = wv.z; w[q * 4 + 3] = wv.w;
    }
#pragma unroll
    for (int r = 0; r < 4; ++r)
#pragma unroll
      for (int c = 0; c < NC; ++c) acc[c] = fmaf(hr[r], w[r * NC + c], acc[c]);
  }

  for (int u = t; u < NG / 4; u += 256) {   // residual head
    u16x4 gv = *(const u16x4*)&g_bf[(size_t)b * KP + u * 4];
    float gr[4] = {bf2f(gv[0]), bf2f(gv[1]), bf2f(gv[2]), bf2f(gv[3])};
    const float4* wp = (const float4*)&Wres[u * 4 * NC];
    float w[40];
#pragma unroll
    for (int q = 0; q < 10; ++q) {
      float4 wv = wp[q];
      w[q * 4] = wv.x; w[q * 4 + 1] = wv.y; w[q * 4 + 2] = wv.z; w[q * 4 + 3] = wv.w;
    }
#pragma unroll
    for (int r = 0; r < 4; ++r)
#pragma unroll
      for (int c = 0; c < NC; ++c) acc[c] = fmaf(gr[r], w[r * NC + c], acc[c]);
  }

  __shared__ float red[4][NC];
  __shared__ float logits[NC];
  int lane = t & 63, wave = t >> 6;
#pragma unroll
  for (int c = 0; c < NC; ++c) {
    float v = acc[c];
    for (int off = 32; off > 0; off >>= 1) v += __shfl_down(v, off, 64);
    if (lane == 0) red[wave][c] = v;
  }
  __syncthreads();
  if (t < NC)
    logits[t] = red[0][t] + red[1][t] + red[2][t] + red[3][t] + bout[t] + bres[t];
  __syncthreads();
  if (t == 0) {
    float mx = logits[0];
#pragma unroll
    for (int c = 1; c < NC; ++c) mx = fmaxf(mx, logits[c]);
    float e[NC], s = 0.f;
#pragma unroll
    for (int c = 0; c < NC; ++c) { e[c] = expf(logits[c] - mx); s += e[c]; }
    float inv = 1.f / s;
#pragma unroll
    for (int c = 0; c < NC; ++c) out[(size_t)b * NC + c] = e[c] * inv;
  }
}

// ---------------------------------------------------------------------------
extern "C" void kernel_launch(void* const* d_in, const int* in_sizes, int n_in,
                              void* d_out, int out_size, void* d_ws, size_t ws_size,
                              hipStream_t stream) {
  const float* x      = (const float*)d_in[0];
  const float* gw     = (const float*)d_in[1];
  const float* gb     = (const float*)d_in[2];
  const float* W1     = (const float*)d_in[3];
  const float* gamma1 = (const float*)d_in[5];
  const float* beta1  = (const float*)d_in[6];
  const float* W2     = (const float*)d_in[7];
  const float* gamma2 = (const float*)d_in[9];
  const float* beta2  = (const float*)d_in[10];
  const float* Wout   = (const float*)d_in[11];
  const float* bout   = (const float*)d_in[12];
  const float* Wres   = (const float*)d_in[13];
  const float* bres   = (const float*)d_in[14];
  float* out = (float*)d_out;

  char* p = (char*)d_ws;
  unsigned short* g_bf = (unsigned short*)p; p += (size_t)NB * KP * 2;    // 4 MB
  unsigned short* W1bT = (unsigned short*)p; p += (size_t)NH1 * KP * 2;   // 4 MB
  unsigned short* W2bT = (unsigned short*)p; p += (size_t)NH2 * NH1 * 2;  // 1 MB
  unsigned short* t1b = (unsigned short*)p; p += (size_t)NB * NH1 * 2;    // 2 MB
  float* t2 = (float*)p; p += (size_t)NB * NH2 * 4;                       // 2 MB
  float* stats = (float*)p;
  float* sum1 = stats, *sq1 = stats + 1024, *sum2 = stats + 2048, *sq2 = stats + 2560;

  // gene + weight-transpose + stats-zero in one dispatch
  prep_kernel<<<dim3(NB, 11), 256, 0, stream>>>(x, gw, gb, g_bf,
                                                W1, W1bT, W2, W2bT, stats);

  gemm1_kernel<<<dim3(NH1 / 64, NB / 32), 256, 0, stream>>>(
      g_bf, W1bT, t1b, sum1, sq1, NB, NH1, KP);

  gemm2_kernel<<<dim3(NH2 / 32, NB / 32), 256, 0, stream>>>(
      t1b, W2bT, t2, sum1, sq1, gamma1, beta1, sum2, sq2, NB, NH2, NH1);

  final_kernel<<<NB, 256, 0, stream>>>(t2, sum2, sq2, gamma2, beta2, g_bf,
                                       Wout, bout, Wres, bres, out);
}

// Round 7
// 363.432 us; speedup vs baseline: 1.3343x; 1.0207x over previous
//
#include <hip/hip_runtime.h>
#include <math.h>

#define NB   1024
#define NG   2000
#define NGS  25
#define KP   2048   // K padded to multiple of 64 for MFMA GEMM1
#define NH1  1024
#define NH2  512
#define NC   10
#define EPSV 1e-5f
#define GPB  200    // gene groups per block

// R5 post-mortem: cooperative grid.sync() fusion cost +119 us -- separate
// kernels are the cheaper grid barrier (~3 us/gap). R6: t1 as bf16 was
// neutral-to-negative -> t1 back to fp32 (R4 config). This round: gemm1
// upgraded to 32x32x16 MFMA (R5-validated math, standalone): 16 frag reads
// per K-iter instead of 24 for the same 262K FLOP.

typedef __attribute__((ext_vector_type(8)))  __bf16 bf16x8;
typedef __attribute__((ext_vector_type(4)))  float  f32x4;
typedef __attribute__((ext_vector_type(16))) float  f32x16;
typedef __attribute__((ext_vector_type(8)))  unsigned short u16x8;
typedef __attribute__((ext_vector_type(4)))  unsigned short u16x4;

__device__ __forceinline__ unsigned short f2bf(float f) {
  union { float f; unsigned u; } v; v.f = f;
  return (unsigned short)((v.u + 0x7fffu + ((v.u >> 16) & 1u)) >> 16);
}
__device__ __forceinline__ float bf2f(unsigned short b) {
  union { unsigned u; float f; } v; v.u = ((unsigned)b) << 16;
  return v.f;
}

// ---------------------------------------------------------------------------
// Prep + gene dispatch. grid (1024, 11):
//   y < 10 : gene layer block (batch row b = x, group-chunk y)
//   y == 10: x<512 -> convT W1 tile; x in [512,640) -> convT W2 tile;
//            x==640 -> zero BN stat accumulators; else idle.
// ---------------------------------------------------------------------------
__global__ __launch_bounds__(256) void prep_kernel(
    const float* __restrict__ x, const float* __restrict__ gw,
    const float* __restrict__ gb, unsigned short* __restrict__ g_bf,
    const float* __restrict__ W1, unsigned short* __restrict__ W1bT,
    const float* __restrict__ W2, unsigned short* __restrict__ W2bT,
    float* __restrict__ stats) {
  __shared__ char smem[GPB * NGS * 4];   // 20 KB, unioned between paths
  int t = threadIdx.x;

  if (blockIdx.y < 10) {                 // ---- gene path
    float* xs = (float*)smem;
    int b = blockIdx.x;
    int blk = blockIdx.y;
    const float4* src = (const float4*)(x + (size_t)b * (NG * NGS) + blk * (GPB * NGS));
    float4* dst = (float4*)xs;
    for (int i = t; i < (GPB * NGS) / 4; i += 256) dst[i] = src[i];
    __syncthreads();
    if (t < GPB) {
      int gi = blk * GPB + t;
      const float* wp = gw + gi * NGS;
      const float* xp = xs + t * NGS;
      float acc = 0.f;
#pragma unroll
      for (int k = 0; k < NGS; ++k) acc = fmaf(xp[k], wp[k], acc);
      acc += gb[gi];
      g_bf[(size_t)b * KP + gi] = f2bf(fmaxf(acc, 0.f));
    } else if (blk == 9 && t < GPB + (KP - NG)) {
      g_bf[(size_t)b * KP + NG + (t - GPB)] = 0;   // zero-pad k 2000..2047
    }
    return;
  }

  // ---- prep path (y == 10)
  int bx = blockIdx.x;
  if (bx == 640) {                       // zero BN stats (3072 floats)
    for (int i = t; i < 3072; i += 256) stats[i] = 0.f;
    return;
  }
  const float* src; unsigned short* dst; int K, N, Kpad, k0, n0;
  if (bx < 512)      { src = W1; dst = W1bT; K = NG;  N = NH1; Kpad = KP;
                       k0 = (bx & 31) * 64; n0 = (bx >> 5) * 64; }
  else if (bx < 640) { int xi = bx - 512;
                       src = W2; dst = W2bT; K = NH1; N = NH2; Kpad = NH1;
                       k0 = (xi & 15) * 64; n0 = (xi >> 4) * 64; }
  else return;

  unsigned short (*ts)[72] = (unsigned short (*)[72])smem;   // 64x72 = 9.2 KB
  int c4 = (t & 15) * 4;
  int r  = t >> 4;
  for (int rr = r; rr < 64; rr += 16) {
    int k = k0 + rr;
    float4 v = make_float4(0.f, 0.f, 0.f, 0.f);
    if (k < K) v = *(const float4*)&src[(size_t)k * N + n0 + c4];
    ts[rr][c4 + 0] = f2bf(v.x); ts[rr][c4 + 1] = f2bf(v.y);
    ts[rr][c4 + 2] = f2bf(v.z); ts[rr][c4 + 3] = f2bf(v.w);
  }
  __syncthreads();
  int rr8 = (t & 7) * 8;
  int cc  = t >> 3;
  for (int c = cc; c < 64; c += 32) {
    u16x8 val;
#pragma unroll
    for (int i = 0; i < 8; ++i) val[i] = ts[rr8 + i][c];
    *(u16x8*)&dst[(size_t)(n0 + c) * Kpad + k0 + rr8] = val;
  }
}

// ---------------------------------------------------------------------------
// GEMM1: t1(fp32) = A(bf16)[M][Kp] * Bt(bf16)[N][Kp]^T, fused BN1 stats.
// 32x64 block tile (grid 512 = 2 blocks/CU), 32x32x16 MFMA. 4 waves:
// h = n-half (32 cols), p = k-phase (32 of the 64-col K-tile). k-phases
// combine through a stride-17 LDS buffer (conflict-free scalar f32).
// Per K-iter: 16 ds_read_b128 + 8 MFMA (vs 24 + 16 for the 16x16x32 form).
// ---------------------------------------------------------------------------
__global__ __launch_bounds__(256) void gemm1_kernel(
    const unsigned short* __restrict__ A,    // [M][Kp]
    const unsigned short* __restrict__ Bt,   // [N][Kp]
    float* __restrict__ C, float* __restrict__ sum, float* __restrict__ sq,
    int M, int N, int Kp) {
  __shared__ unsigned short As[32][68];      // pitch 34 dw (== 2 mod 32)
  __shared__ unsigned short Bs[64][68];
  __shared__ float ebuf[2 * 64 * 17];        // k-phase combine, stride 17
  int t = threadIdx.x;
  int m0 = blockIdx.y * 32, n0 = blockIdx.x * 64;
  int wave = t >> 6, lane = t & 63;
  int h = wave & 1;            // n-half
  int p = wave >> 1;           // k-phase
  int l31 = lane & 31, l5 = lane >> 5;
  int srow = t >> 3, skc = (t & 7) * 8;      // staging: 32 rows x 64 cols

  f32x16 acc;
#pragma unroll
  for (int q = 0; q < 16; ++q) acc[q] = 0.f;

  const unsigned short* Ap = A + (size_t)(m0 + srow) * Kp + skc;
  const unsigned short* Bp = Bt + (size_t)(n0 + srow) * Kp + skc;
  size_t rstep = 32 * (size_t)Kp;

  u16x8 pa0 = *(const u16x8*)(Ap);
  u16x8 pb0 = *(const u16x8*)(Bp);
  u16x8 pb1 = *(const u16x8*)(Bp + rstep);

  for (int k0 = 0; k0 < Kp; k0 += 64) {
    *(u16x8*)&As[srow][skc]      = pa0;
    *(u16x8*)&Bs[srow][skc]      = pb0;
    *(u16x8*)&Bs[srow + 32][skc] = pb1;
    __syncthreads();
    if (k0 + 64 < Kp) {
      pa0 = *(const u16x8*)(Ap + k0 + 64);
      pb0 = *(const u16x8*)(Bp + k0 + 64);
      pb1 = *(const u16x8*)(Bp + k0 + 64 + rstep);
    }
    int kb = p * 32 + l5 * 8;
    {
      bf16x8 av = *(const bf16x8*)&As[l31][kb];
      bf16x8 bv = *(const bf16x8*)&Bs[h * 32 + l31][kb];
      acc = __builtin_amdgcn_mfma_f32_32x32x16_bf16(av, bv, acc, 0, 0, 0);
    }
    {
      bf16x8 av = *(const bf16x8*)&As[l31][kb + 16];
      bf16x8 bv = *(const bf16x8*)&Bs[h * 32 + l31][kb + 16];
      acc = __builtin_amdgcn_mfma_f32_32x32x16_bf16(av, bv, acc, 0, 0, 0);
    }
    __syncthreads();
  }

  // combine k-phases: p=1 publishes, p=0 adds + stores + stats
  float* eb = ebuf + (size_t)(h * 64 + lane) * 17;
  if (p == 1) {
#pragma unroll
    for (int r = 0; r < 16; ++r) eb[r] = acc[r];
  }
  __syncthreads();
  if (p == 0) {
    float s = 0.f, ss = 0.f;
#pragma unroll
    for (int r = 0; r < 16; ++r) {
      float v = acc[r] + eb[r];
      // C/D 32x32: col=lane&31, row=(r&3)+8*(r>>2)+4*(lane>>5)
      int row = m0 + (r & 3) + 8 * (r >> 2) + 4 * l5;
      C[(size_t)row * N + n0 + h * 32 + l31] = v;
      s += v;
      ss = fmaf(v, v, ss);
    }
    s  += __shfl_down(s, 32, 64);
    ss += __shfl_down(ss, 32, 64);
    if (lane < 32) {
      atomicAdd(&sum[n0 + h * 32 + lane], s);
      atomicAdd(&sq[n0 + h * 32 + lane], ss);
    }
  }
}

// ---------------------------------------------------------------------------
// GEMM2: A = t1 fp32, BN1+ReLU applied during LDS staging (-> bf16);
// B = W2bT bf16. Fused BN2 stats. 32x32 tile (grid 512 = 2 blocks/CU),
// 4 waves each 16x16.
// ---------------------------------------------------------------------------
__global__ __launch_bounds__(256) void gemm2_kernel(
    const float* __restrict__ A,             // [M][Kp] fp32 (t1, pre-BN)
    const unsigned short* __restrict__ Bt,   // [N][Kp] bf16
    float* __restrict__ C, const float* __restrict__ sum1,
    const float* __restrict__ sq1, const float* __restrict__ gam1,
    const float* __restrict__ bet1, float* __restrict__ sum2,
    float* __restrict__ sq2, int M, int N, int Kp) {
  __shared__ unsigned short As[32][72];
  __shared__ unsigned short Bs[32][72];
  int t = threadIdx.x;
  int m0 = blockIdx.y * 32, n0 = blockIdx.x * 32;
  int wave = t >> 6, lane = t & 63;
  int wm = (wave >> 1) * 16, wn = (wave & 1) * 16;
  int fm = lane & 15, fk = (lane >> 4) * 8;
  int srow = t >> 3, skc = (t & 7) * 8;    // srow 0..31

  f32x4 acc = (f32x4){0.f, 0.f, 0.f, 0.f};

  const float* Ap = A + (size_t)(m0 + srow) * Kp + skc;
  const unsigned short* Bp = Bt + (size_t)(n0 + srow) * Kp + skc;

  f32x4 pa0 = *(const f32x4*)(Ap);
  f32x4 pa1 = *(const f32x4*)(Ap + 4);
  u16x8 pb0 = *(const u16x8*)(Bp);

  for (int k0 = 0; k0 < Kp; k0 += 64) {
    // BN1 scale/shift for k = k0+skc+i (same 64 values block-wide -> L1 hot)
    float sc[8], sh[8];
#pragma unroll
    for (int i = 0; i < 8; ++i) {
      int k = k0 + skc + i;
      float mu  = sum1[k] * (1.f / NB);
      float var = sq1[k] * (1.f / NB) - mu * mu;
      float rs  = rsqrtf(var + EPSV);
      sc[i] = gam1[k] * rs;
      sh[i] = fmaf(-mu, sc[i], bet1[k]);
    }
    u16x8 a0;
#pragma unroll
    for (int i = 0; i < 4; ++i) {
      a0[i]     = f2bf(fmaxf(fmaf(pa0[i], sc[i],     sh[i]),     0.f));
      a0[i + 4] = f2bf(fmaxf(fmaf(pa1[i], sc[i + 4], sh[i + 4]), 0.f));
    }
    *(u16x8*)&As[srow][skc] = a0;
    *(u16x8*)&Bs[srow][skc] = pb0;
    __syncthreads();
    if (k0 + 64 < Kp) {
      pa0 = *(const f32x4*)(Ap + k0 + 64);
      pa1 = *(const f32x4*)(Ap + k0 + 64 + 4);
      pb0 = *(const u16x8*)(Bp + k0 + 64);
    }
#pragma unroll
    for (int s = 0; s < 2; ++s) {
      bf16x8 af = *(const bf16x8*)&As[wm + fm][s * 32 + fk];
      bf16x8 bf = *(const bf16x8*)&Bs[wn + fm][s * 32 + fk];
      acc = __builtin_amdgcn_mfma_f32_16x16x32_bf16(af, bf, acc, 0, 0, 0);
    }
    __syncthreads();
  }

  int crow = (lane >> 4) * 4, ccol = lane & 15;
  float s = 0.f, ss = 0.f;
#pragma unroll
  for (int r = 0; r < 4; ++r) {
    float v = acc[r];
    int m = m0 + wm + crow + r;
    int n = n0 + wn + ccol;
    C[(size_t)m * N + n] = v;
    s += v;
    ss = fmaf(v, v, ss);
  }
  s  += __shfl_down(s, 32, 64);  s  += __shfl_down(s, 16, 64);
  ss += __shfl_down(ss, 32, 64); ss += __shfl_down(ss, 16, 64);
  if (lane < 16) {
    atomicAdd(&sum2[n0 + wn + lane], s);
    atomicAdd(&sq2[n0 + wn + lane], ss);
  }
}

// ---------------------------------------------------------------------------
// Final: BN2(inline)+ReLU on t2 row, both heads, softmax. Block per row.
// ---------------------------------------------------------------------------
__global__ __launch_bounds__(256) void final_kernel(
    const float* __restrict__ t2, const float* __restrict__ sum2,
    const float* __restrict__ sq2, const float* __restrict__ gam2,
    const float* __restrict__ bet2, const unsigned short* __restrict__ g_bf,
    const float* __restrict__ Wout, const float* __restrict__ bout,
    const float* __restrict__ Wres, const float* __restrict__ bres,
    float* __restrict__ out) {
  int b = blockIdx.x;
  int t = threadIdx.x;
  float acc[NC] = {};

  if (t < NH2 / 4) {   // main head: BN2 inline
    float4 tv = *(const float4*)&t2[(size_t)b * NH2 + t * 4];
    float raw[4] = {tv.x, tv.y, tv.z, tv.w};
    float hr[4];
#pragma unroll
    for (int i = 0; i < 4; ++i) {
      int c = t * 4 + i;
      float mu  = sum2[c] * (1.f / NB);
      float var = sq2[c] * (1.f / NB) - mu * mu;
      float rs  = rsqrtf(var + EPSV);
      float scv = gam2[c] * rs;
      hr[i] = fmaxf(fmaf(raw[i], scv, fmaf(-mu, scv, bet2[c])), 0.f);
    }
    const float4* wp = (const float4*)&Wout[t * 4 * NC];
    float w[40];
#pragma unroll
    for (int q = 0; q < 10; ++q) {
      float4 wv = wp[q];
      w[q * 4] = wv.x; w[q * 4 + 1] = wv.y; w[q * 4 + 2] = wv.z; w[q * 4 + 3] = wv.w;
    }
#pragma unroll
    for (int r = 0; r < 4; ++r)
#pragma unroll
      for (int c = 0; c < NC; ++c) acc[c] = fmaf(hr[r], w[r * NC + c], acc[c]);
  }

  for (int u = t; u < NG / 4; u += 256) {   // residual head
    u16x4 gv = *(const u16x4*)&g_bf[(size_t)b * KP + u * 4];
    float gr[4] = {bf2f(gv[0]), bf2f(gv[1]), bf2f(gv[2]), bf2f(gv[3])};
    const float4* wp = (const float4*)&Wres[u * 4 * NC];
    float w[40];
#pragma unroll
    for (int q = 0; q < 10; ++q) {
      float4 wv = wp[q];
      w[q * 4] = wv.x; w[q * 4 + 1] = wv.y; w[q * 4 + 2] = wv.z; w[q * 4 + 3] = wv.w;
    }
#pragma unroll
    for (int r = 0; r < 4; ++r)
#pragma unroll
      for (int c = 0; c < NC; ++c) acc[c] = fmaf(gr[r], w[r * NC + c], acc[c]);
  }

  __shared__ float red[4][NC];
  __shared__ float logits[NC];
  int lane = t & 63, wave = t >> 6;
#pragma unroll
  for (int c = 0; c < NC; ++c) {
    float v = acc[c];
    for (int off = 32; off > 0; off >>= 1) v += __shfl_down(v, off, 64);
    if (lane == 0) red[wave][c] = v;
  }
  __syncthreads();
  if (t < NC)
    logits[t] = red[0][t] + red[1][t] + red[2][t] + red[3][t] + bout[t] + bres[t];
  __syncthreads();
  if (t == 0) {
    float mx = logits[0];
#pragma unroll
    for (int c = 1; c < NC; ++c) mx = fmaxf(mx, logits[c]);
    float e[NC], s = 0.f;
#pragma unroll
    for (int c = 0; c < NC; ++c) { e[c] = expf(logits[c] - mx); s += e[c]; }
    float inv = 1.f / s;
#pragma unroll
    for (int c = 0; c < NC; ++c) out[(size_t)b * NC + c] = e[c] * inv;
  }
}

// ---------------------------------------------------------------------------
extern "C" void kernel_launch(void* const* d_in, const int* in_sizes, int n_in,
                              void* d_out, int out_size, void* d_ws, size_t ws_size,
                              hipStream_t stream) {
  const float* x      = (const float*)d_in[0];
  const float* gw     = (const float*)d_in[1];
  const float* gb     = (const float*)d_in[2];
  const float* W1     = (const float*)d_in[3];
  const float* gamma1 = (const float*)d_in[5];
  const float* beta1  = (const float*)d_in[6];
  const float* W2     = (const float*)d_in[7];
  const float* gamma2 = (const float*)d_in[9];
  const float* beta2  = (const float*)d_in[10];
  const float* Wout   = (const float*)d_in[11];
  const float* bout   = (const float*)d_in[12];
  const float* Wres   = (const float*)d_in[13];
  const float* bres   = (const float*)d_in[14];
  float* out = (float*)d_out;

  char* p = (char*)d_ws;
  unsigned short* g_bf = (unsigned short*)p; p += (size_t)NB * KP * 2;    // 4 MB
  unsigned short* W1bT = (unsigned short*)p; p += (size_t)NH1 * KP * 2;   // 4 MB
  unsigned short* W2bT = (unsigned short*)p; p += (size_t)NH2 * NH1 * 2;  // 1 MB
  float* t1 = (float*)p; p += (size_t)NB * NH1 * 4;                       // 4 MB
  float* t2 = (float*)p; p += (size_t)NB * NH2 * 4;                       // 2 MB
  float* stats = (float*)p;
  float* sum1 = stats, *sq1 = stats + 1024, *sum2 = stats + 2048, *sq2 = stats + 2560;

  // gene + weight-transpose + stats-zero in one dispatch
  prep_kernel<<<dim3(NB, 11), 256, 0, stream>>>(x, gw, gb, g_bf,
                                                W1, W1bT, W2, W2bT, stats);

  gemm1_kernel<<<dim3(NH1 / 64, NB / 32), 256, 0, stream>>>(
      g_bf, W1bT, t1, sum1, sq1, NB, NH1, KP);

  gemm2_kernel<<<dim3(NH2 / 32, NB / 32), 256, 0, stream>>>(
      t1, W2bT, t2, sum1, sq1, gamma1, beta1, sum2, sq2, NB, NH2, NH1);

  final_kernel<<<NB, 256, 0, stream>>>(t2, sum2, sq2, gamma2, beta2, g_bf,
                                       Wout, bout, Wres, bres, out);
}